// Round 1
// baseline (206.203 us; speedup 1.0000x reference)
//
#include <hip/hip_runtime.h>
#include <math.h>

#define BATCH_N   32768
#define IN_F      784
#define HID_F     256
#define NCLS      10
#define BM        64          // batch rows per block
#define NTHREADS  512         // 8 waves: 2 (row groups) x 4 (col groups)
#define NRND      13          // staging rounds of K=64 (last holds 16 valid k)

typedef __attribute__((ext_vector_type(8))) short short8;  // 8 bf16 = one MFMA operand frag
typedef __attribute__((ext_vector_type(4))) float f32x4;

// d_ws layout: w1 pre-converted to split-bf16 "frag images":
//   slot s = (kt*16 + ct)*64 + lane, 16 B each: B-frag elems j=0..7 =
//   w1[n][k], n = ct*16 + (lane&15), k = kt*32 + (lane>>4)*8 + j  (0 if k>=784)
#define WS_W1H 0
#define WS_W1L 409600          // 25*16*64*16
// total d_ws use: 819200 bytes

union S8U { short8 s; uint4 u; };

// fp32x8 -> split bf16 (hi = truncate, lo = exact residual truncated)
__device__ __forceinline__ void cvt8(float4 a, float4 b, short8* hi, short8* lo) {
    const unsigned M = 0xFFFF0000u;
    const unsigned ux = __float_as_uint(a.x), uy = __float_as_uint(a.y),
                   uz = __float_as_uint(a.z), uw = __float_as_uint(a.w),
                   vx = __float_as_uint(b.x), vy = __float_as_uint(b.y),
                   vz = __float_as_uint(b.z), vw = __float_as_uint(b.w);
    S8U h, l;
    h.u.x = (ux >> 16) | (uy & M);
    h.u.y = (uz >> 16) | (uw & M);
    h.u.z = (vx >> 16) | (vy & M);
    h.u.w = (vz >> 16) | (vw & M);
    const float rx = a.x - __uint_as_float(ux & M);   // exact residuals
    const float ry = a.y - __uint_as_float(uy & M);
    const float rz = a.z - __uint_as_float(uz & M);
    const float rw = a.w - __uint_as_float(uw & M);
    const float sx = b.x - __uint_as_float(vx & M);
    const float sy = b.y - __uint_as_float(vy & M);
    const float sz = b.z - __uint_as_float(vz & M);
    const float sw_ = b.w - __uint_as_float(vw & M);
    l.u.x = (__float_as_uint(rx) >> 16) | (__float_as_uint(ry) & M);
    l.u.y = (__float_as_uint(rz) >> 16) | (__float_as_uint(rw) & M);
    l.u.z = (__float_as_uint(sx) >> 16) | (__float_as_uint(sy) & M);
    l.u.w = (__float_as_uint(sz) >> 16) | (__float_as_uint(sw_) & M);
    *hi = h.s; *lo = l.s;
}

// ---- pre-pass: w1 -> split-bf16 frag images in d_ws (runs every launch) ----
__global__ __launch_bounds__(256)
void prep_w1_kernel(const float* __restrict__ w1, char* __restrict__ ws) {
    const int s    = blockIdx.x * 256 + threadIdx.x;   // 25600 slots
    const int lane = s & 63, ct = (s >> 6) & 15, kt = s >> 10;
    const int n    = ct * 16 + (lane & 15);
    const int k0   = kt * 32 + (lane >> 4) * 8;        // either fully <784 or fully pad
    float4 a = make_float4(0.f, 0.f, 0.f, 0.f), b = a;
    if (k0 + 7 < IN_F) {
        const float* p = w1 + (size_t)n * IN_F + k0;
        a = *(const float4*)p;
        b = *(const float4*)(p + 4);
    }
    short8 hi, lo;
    cvt8(a, b, &hi, &lo);
    *(short8*)(ws + WS_W1H + (size_t)s * 16) = hi;
    *(short8*)(ws + WS_W1L + (size_t)s * 16) = lo;
}

// ---- main kernel: cooperative LDS-staged A, 2x4 wave grid, 16 waves/CU ----
__global__ __launch_bounds__(NTHREADS, 4)
void mlp_mfma_kernel(const float* __restrict__ x,
                     const char*  __restrict__ wsb,
                     const float* __restrict__ b1,
                     const float* __restrict__ w2,
                     const float* __restrict__ b2,
                     float* __restrict__ out)
{
    // staging: x tile 64 rows x 64 K as split bf16, double-buffered, XOR-swizzled.
    // slot(row, ks) = row*8 + (ks ^ (row&7)), ks = k-slot of 8 elems.
    __shared__ short8 xh[2][512];   // 16 KB
    __shared__ short8 xl[2][512];   // 16 KB
    __shared__ float  hid[64 * 128]; // 32 KB: compact col-half per epilogue pass

    const int tid  = threadIdx.x;
    const int lane = tid & 63;
    const int wv   = tid >> 6;
    const int wc   = wv & 3;           // col group: ct = wc*4 + c
    const int wr   = wv >> 2;          // row group: rows wr*32 + rt*16 + ...
    const int m    = lane & 15;
    const int quad = lane >> 4;
    const int row0 = blockIdx.x * BM;

    // cooperative staging mapping: thread -> (row slr, k-slot sks)
    const int slr = tid >> 3;          // 0..63
    const int sks = tid & 7;           // 0..7 (8 floats each)
    const float* xs = x + (size_t)(row0 + slr) * IN_F + sks * 8;
    const int swidx = slr * 8 + (sks ^ (slr & 7));

    // A-frag read slots: lr = wr*32 + rt*16 + m, slot(kk) = (kk*4+quad) ^ (m&7)
    const int rb  = (wr * 32 + m) * 8;
    const int sl0 = rb + (quad ^ (m & 7));         // kk = 0
    const int sl1 = rb + ((4 + quad) ^ (m & 7));   // kk = 1

    // B pointers (w1 frag images)
    const char* bhp = wsb + WS_W1H + ((size_t)(wc * 4) * 64 + lane) * 16;
    const char* blp = wsb + WS_W1L + ((size_t)(wc * 4) * 64 + lane) * 16;

    f32x4 acc[2][4];
    #pragma unroll
    for (int a = 0; a < 2; ++a)
        #pragma unroll
        for (int b = 0; b < 4; ++b)
            acc[a][b] = (f32x4){0.f, 0.f, 0.f, 0.f};

    // ---- prologue: stage round 0 ----
    {
        float4 a = *(const float4*)(xs);
        float4 b = *(const float4*)(xs + 4);
        short8 hi, lo;
        cvt8(a, b, &hi, &lo);
        xh[0][swidx] = hi;
        xl[0][swidx] = lo;
    }
    __syncthreads();

    int cur = 0;
    for (int r = 0; r < NRND - 1; ++r) {           // r = 0..11
        // issue next-round x loads early (hidden under this round's compute)
        const int kn = (r + 1) * 64 + sks * 8;
        float4 xa = make_float4(0.f, 0.f, 0.f, 0.f), xb = xa;
        if (kn + 7 < IN_F) {                       // uniform-true for r<11
            xa = *(const float4*)(xs + (r + 1) * 64);
            xb = *(const float4*)(xs + (r + 1) * 64 + 4);
        }
        // compute kt = 2r, 2r+1 from current buffer
        #pragma unroll
        for (int kk = 0; kk < 2; ++kk) {
            const int kt = r * 2 + kk;
            short8 bh[4], bl[4];
            #pragma unroll
            for (int c = 0; c < 4; ++c) {
                bh[c] = *(const short8*)(bhp + (size_t)kt * 16384 + c * 1024);
                bl[c] = *(const short8*)(blp + (size_t)kt * 16384 + c * 1024);
            }
            const int sl = kk ? sl1 : sl0;
            short8 ah[2], al[2];
            #pragma unroll
            for (int rt = 0; rt < 2; ++rt) {
                ah[rt] = xh[cur][sl + rt * 128];
                al[rt] = xl[cur][sl + rt * 128];
            }
            #pragma unroll
            for (int rt = 0; rt < 2; ++rt)
                #pragma unroll
                for (int c = 0; c < 4; ++c) {
                    acc[rt][c] = __builtin_amdgcn_mfma_f32_16x16x32_bf16(ah[rt], bh[c], acc[rt][c], 0, 0, 0);
                    acc[rt][c] = __builtin_amdgcn_mfma_f32_16x16x32_bf16(al[rt], bh[c], acc[rt][c], 0, 0, 0);
                    acc[rt][c] = __builtin_amdgcn_mfma_f32_16x16x32_bf16(ah[rt], bl[c], acc[rt][c], 0, 0, 0);
                }
        }
        // stage next round into the other buffer; its previous readers finished
        // before the last barrier, so one barrier per round suffices.
        {
            short8 hi, lo;
            cvt8(xa, xb, &hi, &lo);
            xh[cur ^ 1][swidx] = hi;
            xl[cur ^ 1][swidx] = lo;
        }
        __syncthreads();
        cur ^= 1;
    }

    // ---- final round: kt = 24 only (k >= 784 slots are zero-filled) ----
    {
        const int kt = 24;
        short8 bh[4], bl[4];
        #pragma unroll
        for (int c = 0; c < 4; ++c) {
            bh[c] = *(const short8*)(bhp + (size_t)kt * 16384 + c * 1024);
            bl[c] = *(const short8*)(blp + (size_t)kt * 16384 + c * 1024);
        }
        short8 ah[2], al[2];
        #pragma unroll
        for (int rt = 0; rt < 2; ++rt) {
            ah[rt] = xh[cur][sl0 + rt * 128];
            al[rt] = xl[cur][sl0 + rt * 128];
        }
        #pragma unroll
        for (int rt = 0; rt < 2; ++rt)
            #pragma unroll
            for (int c = 0; c < 4; ++c) {
                acc[rt][c] = __builtin_amdgcn_mfma_f32_16x16x32_bf16(ah[rt], bh[c], acc[rt][c], 0, 0, 0);
                acc[rt][c] = __builtin_amdgcn_mfma_f32_16x16x32_bf16(al[rt], bh[c], acc[rt][c], 0, 0, 0);
                acc[rt][c] = __builtin_amdgcn_mfma_f32_16x16x32_bf16(ah[rt], bl[c], acc[rt][c], 0, 0, 0);
            }
    }

    // ---- epilogue: two passes over column halves (hid = 64x128 compact) ----
    const int rl    = tid >> 3;        // row 0..63
    const int slice = tid & 7;         // 8 h-slices per row
    const int gb    = (slice >> 1) * 64 + (slice & 1) * 16;  // + 32p + i*4
    const int cb    = slice * 16;      // compact base
    const int sw2   = (rl & 7) << 2;

    float lg[NCLS];
    #pragma unroll
    for (int k = 0; k < NCLS; ++k) lg[k] = 0.f;

    #pragma unroll
    for (int p = 0; p < 2; ++p) {
        __syncthreads();               // p=1: wait for pass-0 reads before rewrite
        // phase 1: bias + relu -> hid, cols c = 2p, 2p+1 (compact, swizzled)
        #pragma unroll
        for (int cl = 0; cl < 2; ++cl) {
            const int c  = 2 * p + cl;
            const int g  = (wc * 4 + c) * 16 + m;      // global hidden col
            const float bv = b1[g];
            const int cc = wc * 32 + cl * 16 + m;      // compact col
            #pragma unroll
            for (int rt = 0; rt < 2; ++rt)
                #pragma unroll
                for (int reg = 0; reg < 4; ++reg) {
                    const int row = wr * 32 + rt * 16 + quad * 4 + reg;
                    hid[row * 128 + (cc ^ ((row & 7) << 2))] =
                        fmaxf(acc[rt][c][reg] + bv, 0.f);
                }
        }
        __syncthreads();
        // phase 2: partial logits over this pass's 16 compact cols per thread
        #pragma unroll
        for (int i = 0; i < 4; ++i) {
            const float4 h = *(const float4*)(hid + rl * 128 + ((cb + i * 4) ^ sw2));
            const int g4 = gb + 32 * p + i * 4;
            #pragma unroll
            for (int k = 0; k < NCLS; ++k) {
                const float4 w = *(const float4*)(w2 + k * HID_F + g4);
                lg[k] += h.x * w.x + h.y * w.y + h.z * w.z + h.w * w.w;
            }
        }
    }

    // butterfly-reduce the 8 slices (lane bits 0..2), add bias
    #pragma unroll
    for (int k = 0; k < NCLS; ++k) {
        float v = lg[k];
        v += __shfl_xor(v, 1);
        v += __shfl_xor(v, 2);
        v += __shfl_xor(v, 4);
        lg[k] = v + b2[k];
    }
    // softmax (computed redundantly by all 8 slice-lanes of a row)
    float mx = -1e30f;
    #pragma unroll
    for (int k = 0; k < NCLS; ++k) mx = fmaxf(mx, lg[k]);
    float s = 0.f;
    #pragma unroll
    for (int k = 0; k < NCLS; ++k) { lg[k] = __expf(lg[k] - mx); s += lg[k]; }
    const float inv = 1.f / s;
    float* o = out + (size_t)(row0 + rl) * NCLS;
    o[slice] = lg[slice] * inv;                       // classes 0..7
    if (slice < 2) o[8 + slice] = lg[8 + slice] * inv; // classes 8,9
}

extern "C" void kernel_launch(void* const* d_in, const int* in_sizes, int n_in,
                              void* d_out, int out_size, void* d_ws, size_t ws_size,
                              hipStream_t stream)
{
    const float* x  = (const float*)d_in[0];
    const float* w1 = (const float*)d_in[1];
    const float* b1 = (const float*)d_in[2];
    const float* w2 = (const float*)d_in[3];
    const float* b2 = (const float*)d_in[4];
    float* out = (float*)d_out;

    // pre-pass: w1 -> split-bf16 frag images (25600 slots; runs every call)
    hipLaunchKernelGGL(prep_w1_kernel, dim3(100), dim3(256), 0, stream,
                       w1, (char*)d_ws);
    // main fused MLP
    hipLaunchKernelGGL(mlp_mfma_kernel, dim3(BATCH_N / BM), dim3(NTHREADS), 0, stream,
                       x, (const char*)d_ws, b1, w2, b2, out);
}